// Round 15
// baseline (57.383 us; speedup 1.0000x reference)
//
#include <hip/hip_runtime.h>
#include <stdint.h>

#define NATOMS 4096
#define NCELLS 8000
#define KTOP 5
#define MNBR 8
#define NBRC 26
#define HBINS 184          // exact window bound: Dmax-lo <= 4*sumL - 2*minL - 9 <= 181
#define LSTMAX 512

__device__ __forceinline__ unsigned long long umax64(unsigned long long a, unsigned long long b) {
    return a > b ? a : b;
}
__device__ __forceinline__ unsigned long long umin64(unsigned long long a, unsigned long long b) {
    return a < b ? a : b;
}

// cells[m] = (g[b], g[c], g[a]) with m = a*400 + b*20 + c, g[t] = t-10
__device__ __forceinline__ void cell_coords_i(int m, int& x, int& y, int& z) {
    int a = m / 400;
    int r = m - a * 400;
    int b = r / 20;
    int c = r - b * 20;
    x = b - 10; y = c - 10; z = a - 10;
}

// ---------------------------------------------------------------------------
// Kernel 1 (fused): block b = atom b.  (unchanged from r14)
//  wave 0: analytic argmin cell -> ci; writes c4[atom]={x,y,z,|a|^2}.
//  all waves: top-26 LARGEST cell-cell sq-dists for ci (closed-form lo,
//  V-shape enumeration, windowed histogram -> V -> collect -> rank-select;
//  key (d desc, j asc) == jax.lax.top_k tie order).
//  neededFlag marks monotone + identical inputs -> no pre-zeroing.
//  NO cross-block sync (r7/r10: agent-scope fences/RMWs > kernel boundary).
// ---------------------------------------------------------------------------
__global__ __launch_bounds__(256) void k1_cells_nbr(const float* __restrict__ coords,
                                                    int* __restrict__ cellsForAtoms,
                                                    float4* __restrict__ c4,
                                                    int* __restrict__ nbrTable,
                                                    int* __restrict__ neededFlag) {
    const int atom = blockIdx.x;
    const int t = threadIdx.x;
    const int lane = t & 63;

    __shared__ int sCi;
    __shared__ uint32_t h[HBINS];
    __shared__ int lst[LSTMAX];
    __shared__ int sV, cnt;

    if (t < HBINS) h[t] = 0;
    if (t == 0) cnt = 0;

    if (t < 64) {
        float ax = coords[atom * 3], ay = coords[atom * 3 + 1], az = coords[atom * 3 + 2];
        float sa = __fadd_rn(__fadd_rn(__fmul_rn(ax, ax), __fmul_rn(ay, ay)), __fmul_rn(az, az));

        int fx = (int)floorf(ax), fy = (int)floorf(ay), fz = (int)floorf(az);
        int vx = min(9, max(-10, fx - 1 + (lane & 3)));
        int vy = min(9, max(-10, fy - 1 + ((lane >> 2) & 3)));
        int vz = min(9, max(-10, fz - 1 + (lane >> 4)));
        int m = (vz + 10) * 400 + (vx + 10) * 20 + (vy + 10);

        float cx = (float)vx, cy = (float)vy, cz = (float)vz;
        float scell = (float)(vx * vx + vy * vy + vz * vz);
        float dot = __fadd_rn(__fadd_rn(__fmul_rn(ax, cx), __fmul_rn(ay, cy)), __fmul_rn(az, cz));
        float val = __fsub_rn(__fadd_rn(sa, scell), __fmul_rn(2.0f, dot));
        unsigned long long key = ((unsigned long long)__float_as_uint(val) << 32) | (unsigned int)m;

        for (int off = 32; off > 0; off >>= 1)
            key = umin64(key, (unsigned long long)__shfl_xor((long long)key, off));
        if (lane == 0) {
            int c = (int)(key & 0xFFFFFFFFull);
            cellsForAtoms[atom] = c;
            c4[atom] = make_float4(ax, ay, az, sa);
            sCi = c;
        }
    }
    __syncthreads();

    const int ci = sCi;
    int xi, yi, zi;
    cell_coords_i(ci, xi, yi, zi);
    const int Lx = max(xi + 10, 9 - xi);
    const int Ly = max(yi + 10, 9 - yi);
    const int Lz = max(zi + 10, 9 - zi);
    const int lo = (Lx - 2) * (Lx - 2) + (Ly - 2) * (Ly - 2) + (Lz - 2) * (Lz - 2)
                 + 2 * min(Lx, min(Ly, Lz)) - 3;
    const int A0 = zi + 10;

    // pass A: histogram all d >= lo (early-break V-shape enumeration)
#pragma unroll
    for (int col = 0; col < 2; ++col) {
        int p = t + 256 * col;
        if (p < 400) {
            int bb = p / 20, cc = p - bb * 20;
            int dxv = xi - (bb - 10), dyv = yi - (cc - 10);
            int Dbc = dxv * dxv + dyv * dyv;
            int a = 0;
            for (; a < 20; ++a) {
                int dz = A0 - a;
                int d = Dbc + dz * dz;
                if (d < lo) break;
                atomicAdd(&h[d - lo], 1u);
            }
            if (a < 20) {
                for (int a2 = 19; a2 >= a; --a2) {
                    int dz = A0 - a2;
                    int d = Dbc + dz * dz;
                    if (d < lo) break;
                    atomicAdd(&h[d - lo], 1u);
                }
            }
        }
    }
    __syncthreads();

    // single-wave descending scan: V = largest value with suffix-count >= 26
    if (t < 64) {
        int c4b[4];
        int cnt4 = 0;
#pragma unroll
        for (int k = 0; k < 4; ++k) {
            int b = (HBINS - 1) - (t * 4 + k);
            c4b[k] = (b >= 0) ? (int)h[b] : 0;
            cnt4 += c4b[k];
        }
        int incl = cnt4;
        for (int off = 1; off < 64; off <<= 1) {
            int v = __shfl_up(incl, off);
            if (lane >= off) incl += v;
        }
        int P = incl - cnt4;
        if (P < NBRC && incl >= NBRC) {
            int run = P;
#pragma unroll
            for (int k = 0; k < 4; ++k) {
                run += c4b[k];
                if (run >= NBRC) { sV = lo + (HBINS - 1) - (t * 4 + k); break; }
            }
        }
    }
    __syncthreads();
    const int V = sV;

    // pass B: push all d >= V (~30-60 items; plain LDS atomic is cheapest)
#pragma unroll
    for (int col = 0; col < 2; ++col) {
        int p = t + 256 * col;
        if (p < 400) {
            int bb = p / 20, cc = p - bb * 20;
            int dxv = xi - (bb - 10), dyv = yi - (cc - 10);
            int Dbc = dxv * dxv + dyv * dyv;
            int a = 0;
            for (; a < 20; ++a) {
                int dz = A0 - a;
                int d = Dbc + dz * dz;
                if (d < V) break;
                int q = atomicAdd(&cnt, 1);
                if (q < LSTMAX) lst[q] = (d << 13) | (8191 - (a * 400 + p));
            }
            if (a < 20) {
                for (int a2 = 19; a2 >= a; --a2) {
                    int dz = A0 - a2;
                    int d = Dbc + dz * dz;
                    if (d < V) break;
                    int q = atomicAdd(&cnt, 1);
                    if (q < LSTMAX) lst[q] = (d << 13) | (8191 - (a2 * 400 + p));
                }
            }
        }
    }
    __syncthreads();

    // 256-thread rank selection: ranks 0..25 are the top-26 in key order
    int n = min(cnt, LSTMAX);
    for (int idx = t; idx < n; idx += 256) {
        int key = lst[idx];
        int rank = 0;
        for (int m = 0; m < n; ++m) rank += (lst[m] > key) ? 1 : 0;
        if (rank < NBRC) {
            int j = 8191 - (key & 8191);
            nbrTable[ci * NBRC + rank] = j;
            neededFlag[j] = 1;
        }
    }
}

// ---------------------------------------------------------------------------
// Kernel 2 (rewritten): ONE WAVE PER CELL, 4 cells/block, grid 2000.
// No LDS, no barriers; inactive waves exit immediately (uniform per-wave
// branch). Each lane: incremental sorted top-5 of its 64 candidates
// (steady-state 1 compare/atom), then 5 shuffle-only extraction rounds of
// lane heads. Keys unique per cell -> pop-by-equality race-free; key
// (val_bits<<32)|(4095-j) == jax.lax.top_k order (val desc, j asc).
// Per-lane top-5 superset argument: wave top-5 ⊆ union of lane top-5s.
// r13 lesson respected: no serialization — all cells still parallel (waves).
// ---------------------------------------------------------------------------
__global__ __launch_bounds__(256) void k2_atoms(const float4* __restrict__ c4,
                                                const int* __restrict__ neededFlag,
                                                int* __restrict__ atomsInCells) {
    const int wv = threadIdx.x >> 6;
    const int lane = threadIdx.x & 63;
    const int i = blockIdx.x * 4 + wv;          // 2000*4 = 8000 cells exactly
    if (neededFlag[i] != 1) return;             // wave-uniform exit

    int xi_, yi_, zi_;
    cell_coords_i(i, xi_, yi_, zi_);
    const float cx = (float)xi_, cy = (float)yi_, cz = (float)zi_;
    const float scell = (float)(xi_ * xi_ + yi_ * yi_ + zi_ * zi_);

    unsigned long long s0 = 0, s1 = 0, s2 = 0, s3 = 0, s4 = 0;  // desc sorted
    for (int it = 0; it < NATOMS / 64; ++it) {
        int j = lane + 64 * it;                  // coalesced 1KB/wave/iter
        float4 v = c4[j];
        float dot = __fadd_rn(__fadd_rn(__fmul_rn(cx, v.x), __fmul_rn(cy, v.y)),
                              __fmul_rn(cz, v.z));
        float val = __fsub_rn(__fadd_rn(scell, v.w), __fmul_rn(2.0f, dot));
        unsigned long long key =
            ((unsigned long long)__float_as_uint(val) << 32) | (unsigned int)(4095 - j);
        if (key > s4) {                          // sorted insert (rare at steady state)
            if (key > s0)      { s4 = s3; s3 = s2; s2 = s1; s1 = s0; s0 = key; }
            else if (key > s1) { s4 = s3; s3 = s2; s2 = s1; s1 = key; }
            else if (key > s2) { s4 = s3; s3 = s2; s2 = key; }
            else if (key > s3) { s4 = s3; s3 = key; }
            else               { s4 = key; }
        }
    }

    // 5 extraction rounds: wave max of lane heads, owning lane pops
#pragma unroll
    for (int r = 0; r < KTOP; ++r) {
        unsigned long long best = s0;
        for (int off = 32; off > 0; off >>= 1)
            best = umax64(best, (unsigned long long)__shfl_xor((long long)best, off));
        if (s0 == best) { s0 = s1; s1 = s2; s2 = s3; s3 = s4; s4 = 0; }
        if (lane == 0)
            atomsInCells[i * KTOP + r] = 4095 - (int)(best & 0xFFFFFFFFull);
    }
}

// ---------------------------------------------------------------------------
// Kernel 3: per-atom gather of 130 candidates (float4 loads), top-8 LARGEST
// (tie: lower flat position), then energy partial -> plain store. (unchanged)
// ---------------------------------------------------------------------------
__global__ __launch_bounds__(256) void k3_energy(const float4* __restrict__ c4,
                                                 const float* __restrict__ vdw,
                                                 const float* __restrict__ weights,
                                                 const int* __restrict__ nbrTable,
                                                 const int* __restrict__ atomsInCells,
                                                 const int* __restrict__ cellsForAtoms,
                                                 float* __restrict__ partials) {
    const int wid = threadIdx.x >> 6;
    const int lane = threadIdx.x & 63;
    const int i = blockIdx.x * 4 + wid;

    const float4 vi4 = c4[i];
    const float xi = vi4.x, yi = vi4.y, zi = vi4.z;
    const int ci = cellsForAtoms[i];

    int cand[3];
    unsigned long long keys[3];
#pragma unroll
    for (int s = 0; s < 3; ++s) {
        int p = lane + 64 * s;
        cand[s] = -1;
        keys[s] = 0ull;
        if (p < NBRC * KTOP) {
            int cellSlot = p / KTOP;
            int atomSlot = p - cellSlot * KTOP;
            int nc = nbrTable[ci * NBRC + cellSlot];
            int j = atomsInCells[nc * KTOP + atomSlot];
            cand[s] = j;
            float4 vj = c4[j];
            float dx = __fsub_rn(xi, vj.x);
            float dy = __fsub_rn(yi, vj.y);
            float dz = __fsub_rn(zi, vj.z);
            float dist = __fadd_rn(__fadd_rn(__fmul_rn(dx, dx), __fmul_rn(dy, dy)), __fmul_rn(dz, dz));
            keys[s] = ((unsigned long long)__float_as_uint(dist) << 8) | (unsigned int)(255 - p);
        }
    }

    const float w0 = weights[0], w1 = weights[1], w2 = weights[2];
    const float w3 = weights[3], w4 = weights[4];
    const float vi = vdw[i];

    float esum = 0.0f;
    for (int r = 0; r < MNBR; ++r) {
        unsigned long long best = umax64(umax64(keys[0], keys[1]), keys[2]);
        for (int off = 32; off > 0; off >>= 1)
            best = umax64(best, (unsigned long long)__shfl_xor((long long)best, off));

        int p = 255 - (int)(best & 0xFFull);
        int slot = p >> 6;
        int owner = p & 63;
        int jsel = (slot == 0) ? cand[0] : (slot == 1) ? cand[1] : cand[2];
        int j = __shfl(jsel, owner);
        float dist = __uint_as_float((unsigned int)(best >> 8));

#pragma unroll
        for (int s = 0; s < 3; ++s) if (keys[s] == best) keys[s] = 0ull;

        float rr = __fsqrt_rn(__fadd_rn(dist, 1e-12f));
        float d = __fsub_rn(__fsub_rn(rr, vi), vdw[j]);
        float t1 = __fdiv_rn(d, 0.5f);
        float g1 = expf(-__fmul_rn(t1, t1));
        float t2 = __fdiv_rn(__fsub_rn(d, 3.0f), 2.0f);
        float g2 = expf(-__fmul_rn(t2, t2));
        float rep = (d < 0.0f) ? __fmul_rn(d, d) : 0.0f;
        float hyd = (d < 0.5f) ? 1.0f : ((d < 1.5f) ? __fsub_rn(1.5f, d) : 0.0f);
        float hb = (d < -0.7f) ? 1.0f : ((d < 0.0f) ? __fdiv_rn(-d, 0.7f) : 0.0f);
        float hval = __fadd_rn(__fadd_rn(__fadd_rn(__fadd_rn(
                         __fmul_rn(w0, g1), __fmul_rn(w1, g2)),
                         __fmul_rn(w2, rep)), __fmul_rn(w3, hyd)), __fmul_rn(w4, hb));
        float f = (d < 8.0f) ? hval : 0.0f;
        esum = __fadd_rn(esum, f);
    }
    if (lane == 0) partials[i] = esum;
}

// ---------------------------------------------------------------------------
// Kernel 4: deterministic tree reduction + final division. (unchanged)
// ---------------------------------------------------------------------------
__global__ __launch_bounds__(256) void k4_reduce(const float* __restrict__ partials,
                                                 const float* __restrict__ weights,
                                                 const float* __restrict__ nrot,
                                                 float* __restrict__ out) {
    __shared__ float red[256];
    const int t = threadIdx.x;
    float s = 0.0f;
    for (int k = 0; k < NATOMS / 256; ++k) s = __fadd_rn(s, partials[t + 256 * k]);
    red[t] = s;
    __syncthreads();
    for (int off = 128; off > 0; off >>= 1) {
        if (t < off) red[t] = __fadd_rn(red[t], red[t + off]);
        __syncthreads();
    }
    if (t == 0) out[0] = __fdiv_rn(red[0], __fadd_rn(1.0f, __fmul_rn(weights[5], nrot[0])));
}

extern "C" void kernel_launch(void* const* d_in, const int* in_sizes, int n_in,
                              void* d_out, int out_size, void* d_ws, size_t ws_size,
                              hipStream_t stream) {
    const float* coords  = (const float*)d_in[0];
    const float* vdw     = (const float*)d_in[1];
    const float* weights = (const float*)d_in[2];
    const float* nrot    = (const float*)d_in[3];
    float* out = (float*)d_out;

    int* nbrTable      = (int*)d_ws;                       // 208000 ints
    int* atomsInCells  = nbrTable + NCELLS * NBRC;         // 40000
    int* cellsForAtoms = atomsInCells + NCELLS * KTOP;     // 4096
    int* neededFlag    = cellsForAtoms + NATOMS;           // 8000
    float* partials    = (float*)(neededFlag + NCELLS);    // 4096
    float4* c4         = (float4*)(partials + NATOMS);     // 4096 float4 (16B-aligned)

    k1_cells_nbr<<<NATOMS, 256, 0, stream>>>(coords, cellsForAtoms, c4,
                                             nbrTable, neededFlag);
    k2_atoms<<<NCELLS / 4, 256, 0, stream>>>(c4, neededFlag, atomsInCells);
    k3_energy<<<NATOMS / 4, 256, 0, stream>>>(c4, vdw, weights, nbrTable,
                                              atomsInCells, cellsForAtoms, partials);
    k4_reduce<<<1, 256, 0, stream>>>(partials, weights, nrot, out);
}

// Round 16
// 39.349 us; speedup vs baseline: 1.4583x; 1.4583x over previous
//
#include <hip/hip_runtime.h>
#include <stdint.h>

#define NATOMS 4096
#define NCELLS 8000
#define KTOP 5
#define MNBR 8
#define NBRC 26
#define HBINS 184          // exact window bound: Dmax-lo <= 4*sumL - 2*minL - 9 <= 181
#define LSTMAX 512

__device__ __forceinline__ unsigned long long umax64(unsigned long long a, unsigned long long b) {
    return a > b ? a : b;
}
__device__ __forceinline__ unsigned long long umin64(unsigned long long a, unsigned long long b) {
    return a < b ? a : b;
}

// cells[m] = (g[b], g[c], g[a]) with m = a*400 + b*20 + c, g[t] = t-10
__device__ __forceinline__ void cell_coords_i(int m, int& x, int& y, int& z) {
    int a = m / 400;
    int r = m - a * 400;
    int b = r / 20;
    int c = r - b * 20;
    x = b - 10; y = c - 10; z = a - 10;
}

// ---------------------------------------------------------------------------
// Kernel 1 (fused): block b = atom b.
//  wave 0: analytic argmin cell (4x4x4 nbhd of floor(atom); exact d^2 gap
//          >= 1.0 >> f32 err; same f32 formula + min-key as the full scan
//          -> bitwise identical) -> ci; writes c4[atom]={x,y,z,|a|^2}.
//  all waves: top-26 LARGEST cell-cell sq-dists for ci (closed-form lo,
//  V-shape enumeration, windowed histogram -> V -> collect -> rank-select;
//  key (d desc, j asc) == jax.lax.top_k tie order).
//  neededFlag marks monotone + identical inputs -> no pre-zeroing.
//  NO cross-block sync (r7/r10: agent-scope fences/RMWs > kernel boundary).
// ---------------------------------------------------------------------------
__global__ __launch_bounds__(256) void k1_cells_nbr(const float* __restrict__ coords,
                                                    int* __restrict__ cellsForAtoms,
                                                    float4* __restrict__ c4,
                                                    int* __restrict__ nbrTable,
                                                    int* __restrict__ neededFlag) {
    const int atom = blockIdx.x;
    const int t = threadIdx.x;
    const int lane = t & 63;

    __shared__ int sCi;
    __shared__ uint32_t h[HBINS];
    __shared__ int lst[LSTMAX];
    __shared__ int sV, cnt;

    if (t < HBINS) h[t] = 0;
    if (t == 0) cnt = 0;

    if (t < 64) {
        float ax = coords[atom * 3], ay = coords[atom * 3 + 1], az = coords[atom * 3 + 2];
        float sa = __fadd_rn(__fadd_rn(__fmul_rn(ax, ax), __fmul_rn(ay, ay)), __fmul_rn(az, az));

        int fx = (int)floorf(ax), fy = (int)floorf(ay), fz = (int)floorf(az);
        int vx = min(9, max(-10, fx - 1 + (lane & 3)));
        int vy = min(9, max(-10, fy - 1 + ((lane >> 2) & 3)));
        int vz = min(9, max(-10, fz - 1 + (lane >> 4)));
        int m = (vz + 10) * 400 + (vx + 10) * 20 + (vy + 10);

        float cx = (float)vx, cy = (float)vy, cz = (float)vz;
        float scell = (float)(vx * vx + vy * vy + vz * vz);
        float dot = __fadd_rn(__fadd_rn(__fmul_rn(ax, cx), __fmul_rn(ay, cy)), __fmul_rn(az, cz));
        float val = __fsub_rn(__fadd_rn(sa, scell), __fmul_rn(2.0f, dot));
        unsigned long long key = ((unsigned long long)__float_as_uint(val) << 32) | (unsigned int)m;

        for (int off = 32; off > 0; off >>= 1)
            key = umin64(key, (unsigned long long)__shfl_xor((long long)key, off));
        if (lane == 0) {
            int c = (int)(key & 0xFFFFFFFFull);
            cellsForAtoms[atom] = c;
            c4[atom] = make_float4(ax, ay, az, sa);
            sCi = c;
        }
    }
    __syncthreads();

    const int ci = sCi;
    int xi, yi, zi;
    cell_coords_i(ci, xi, yi, zi);
    const int Lx = max(xi + 10, 9 - xi);
    const int Ly = max(yi + 10, 9 - yi);
    const int Lz = max(zi + 10, 9 - zi);
    const int lo = (Lx - 2) * (Lx - 2) + (Ly - 2) * (Ly - 2) + (Lz - 2) * (Lz - 2)
                 + 2 * min(Lx, min(Ly, Lz)) - 3;
    const int A0 = zi + 10;

    // pass A: histogram all d >= lo (early-break V-shape enumeration)
#pragma unroll
    for (int col = 0; col < 2; ++col) {
        int p = t + 256 * col;
        if (p < 400) {
            int bb = p / 20, cc = p - bb * 20;
            int dxv = xi - (bb - 10), dyv = yi - (cc - 10);
            int Dbc = dxv * dxv + dyv * dyv;
            int a = 0;
            for (; a < 20; ++a) {
                int dz = A0 - a;
                int d = Dbc + dz * dz;
                if (d < lo) break;
                atomicAdd(&h[d - lo], 1u);
            }
            if (a < 20) {
                for (int a2 = 19; a2 >= a; --a2) {
                    int dz = A0 - a2;
                    int d = Dbc + dz * dz;
                    if (d < lo) break;
                    atomicAdd(&h[d - lo], 1u);
                }
            }
        }
    }
    __syncthreads();

    // single-wave descending scan: V = largest value with suffix-count >= 26
    if (t < 64) {
        int c4b[4];
        int cnt4 = 0;
#pragma unroll
        for (int k = 0; k < 4; ++k) {
            int b = (HBINS - 1) - (t * 4 + k);
            c4b[k] = (b >= 0) ? (int)h[b] : 0;
            cnt4 += c4b[k];
        }
        int incl = cnt4;
        for (int off = 1; off < 64; off <<= 1) {
            int v = __shfl_up(incl, off);
            if (lane >= off) incl += v;
        }
        int P = incl - cnt4;
        if (P < NBRC && incl >= NBRC) {
            int run = P;
#pragma unroll
            for (int k = 0; k < 4; ++k) {
                run += c4b[k];
                if (run >= NBRC) { sV = lo + (HBINS - 1) - (t * 4 + k); break; }
            }
        }
    }
    __syncthreads();
    const int V = sV;

    // pass B: push all d >= V (~30-60 items; plain LDS atomic is cheapest)
#pragma unroll
    for (int col = 0; col < 2; ++col) {
        int p = t + 256 * col;
        if (p < 400) {
            int bb = p / 20, cc = p - bb * 20;
            int dxv = xi - (bb - 10), dyv = yi - (cc - 10);
            int Dbc = dxv * dxv + dyv * dyv;
            int a = 0;
            for (; a < 20; ++a) {
                int dz = A0 - a;
                int d = Dbc + dz * dz;
                if (d < V) break;
                int q = atomicAdd(&cnt, 1);
                if (q < LSTMAX) lst[q] = (d << 13) | (8191 - (a * 400 + p));
            }
            if (a < 20) {
                for (int a2 = 19; a2 >= a; --a2) {
                    int dz = A0 - a2;
                    int d = Dbc + dz * dz;
                    if (d < V) break;
                    int q = atomicAdd(&cnt, 1);
                    if (q < LSTMAX) lst[q] = (d << 13) | (8191 - (a2 * 400 + p));
                }
            }
        }
    }
    __syncthreads();

    // 256-thread rank selection: ranks 0..25 are the top-26 in key order
    int n = min(cnt, LSTMAX);
    for (int idx = t; idx < n; idx += 256) {
        int key = lst[idx];
        int rank = 0;
        for (int m = 0; m < n; ++m) rank += (lst[m] > key) ? 1 : 0;
        if (rank < NBRC) {
            int j = 8191 - (key & 8191);
            nbrTable[ci * NBRC + rank] = j;
            neededFlag[j] = 1;
        }
    }
}

// ---------------------------------------------------------------------------
// Kernel 2 (r14 formulation — best known): one cell per block, grid 8000,
// early exit; 4 waves split the 4096 atoms (16 coalesced float4 iters each —
// keeps parallel width; r13/r15 lesson: never trade width for op savings).
// Wave-local top-5 (shuffle-only), ONE barrier, 20-key rank-select merge.
// Keys unique -> exact top_k order (val desc, atom idx asc).
// ---------------------------------------------------------------------------
__global__ __launch_bounds__(256) void k2_atoms(const float4* __restrict__ c4,
                                                const int* __restrict__ neededFlag,
                                                int* __restrict__ atomsInCells) {
    const int i = blockIdx.x;
    if (neededFlag[i] != 1) return;
    __shared__ unsigned long long wl[4 * KTOP];
    const int t = threadIdx.x;
    const int lane = t & 63, wv = t >> 6;

    int xi_, yi_, zi_;
    cell_coords_i(i, xi_, yi_, zi_);
    const float cx = (float)xi_, cy = (float)yi_, cz = (float)zi_;
    const float scell = (float)(xi_ * xi_ + yi_ * yi_ + zi_ * zi_);

    unsigned long long keys[16];
#pragma unroll
    for (int s = 0; s < 16; ++s) {
        int j = t + 256 * s;
        float4 v = c4[j];
        float dot = __fadd_rn(__fadd_rn(__fmul_rn(cx, v.x), __fmul_rn(cy, v.y)),
                              __fmul_rn(cz, v.z));
        float val = __fsub_rn(__fadd_rn(scell, v.w), __fmul_rn(2.0f, dot));
        keys[s] = ((unsigned long long)__float_as_uint(val) << 32) | (unsigned int)(4095 - j);
    }

    for (int r = 0; r < KTOP; ++r) {
        unsigned long long best = 0ull;
#pragma unroll
        for (int s = 0; s < 16; ++s) best = umax64(best, keys[s]);
        for (int off = 32; off > 0; off >>= 1)
            best = umax64(best, (unsigned long long)__shfl_xor((long long)best, off));
        if (lane == 0) wl[wv * KTOP + r] = best;
#pragma unroll
        for (int s = 0; s < 16; ++s) if (keys[s] == best) keys[s] = 0ull;
    }
    __syncthreads();

    if (t < 4 * KTOP) {
        unsigned long long key = wl[t];
        int rank = 0;
        for (int m = 0; m < 4 * KTOP; ++m) rank += (wl[m] > key) ? 1 : 0;
        if (rank < KTOP) atomsInCells[i * KTOP + rank] = 4095 - (int)(key & 0xFFFFFFFFull);
    }
}

// ---------------------------------------------------------------------------
// Kernel 3: per-atom gather of 130 candidates (float4 loads), top-8 LARGEST
// (tie: lower flat position), then energy partial -> plain store.
// ---------------------------------------------------------------------------
__global__ __launch_bounds__(256) void k3_energy(const float4* __restrict__ c4,
                                                 const float* __restrict__ vdw,
                                                 const float* __restrict__ weights,
                                                 const int* __restrict__ nbrTable,
                                                 const int* __restrict__ atomsInCells,
                                                 const int* __restrict__ cellsForAtoms,
                                                 float* __restrict__ partials) {
    const int wid = threadIdx.x >> 6;
    const int lane = threadIdx.x & 63;
    const int i = blockIdx.x * 4 + wid;

    const float4 vi4 = c4[i];
    const float xi = vi4.x, yi = vi4.y, zi = vi4.z;
    const int ci = cellsForAtoms[i];

    int cand[3];
    unsigned long long keys[3];
#pragma unroll
    for (int s = 0; s < 3; ++s) {
        int p = lane + 64 * s;
        cand[s] = -1;
        keys[s] = 0ull;
        if (p < NBRC * KTOP) {
            int cellSlot = p / KTOP;
            int atomSlot = p - cellSlot * KTOP;
            int nc = nbrTable[ci * NBRC + cellSlot];
            int j = atomsInCells[nc * KTOP + atomSlot];
            cand[s] = j;
            float4 vj = c4[j];
            float dx = __fsub_rn(xi, vj.x);
            float dy = __fsub_rn(yi, vj.y);
            float dz = __fsub_rn(zi, vj.z);
            float dist = __fadd_rn(__fadd_rn(__fmul_rn(dx, dx), __fmul_rn(dy, dy)), __fmul_rn(dz, dz));
            keys[s] = ((unsigned long long)__float_as_uint(dist) << 8) | (unsigned int)(255 - p);
        }
    }

    const float w0 = weights[0], w1 = weights[1], w2 = weights[2];
    const float w3 = weights[3], w4 = weights[4];
    const float vi = vdw[i];

    float esum = 0.0f;
    for (int r = 0; r < MNBR; ++r) {
        unsigned long long best = umax64(umax64(keys[0], keys[1]), keys[2]);
        for (int off = 32; off > 0; off >>= 1)
            best = umax64(best, (unsigned long long)__shfl_xor((long long)best, off));

        int p = 255 - (int)(best & 0xFFull);
        int slot = p >> 6;
        int owner = p & 63;
        int jsel = (slot == 0) ? cand[0] : (slot == 1) ? cand[1] : cand[2];
        int j = __shfl(jsel, owner);
        float dist = __uint_as_float((unsigned int)(best >> 8));

#pragma unroll
        for (int s = 0; s < 3; ++s) if (keys[s] == best) keys[s] = 0ull;

        float rr = __fsqrt_rn(__fadd_rn(dist, 1e-12f));
        float d = __fsub_rn(__fsub_rn(rr, vi), vdw[j]);
        float t1 = __fdiv_rn(d, 0.5f);
        float g1 = expf(-__fmul_rn(t1, t1));
        float t2 = __fdiv_rn(__fsub_rn(d, 3.0f), 2.0f);
        float g2 = expf(-__fmul_rn(t2, t2));
        float rep = (d < 0.0f) ? __fmul_rn(d, d) : 0.0f;
        float hyd = (d < 0.5f) ? 1.0f : ((d < 1.5f) ? __fsub_rn(1.5f, d) : 0.0f);
        float hb = (d < -0.7f) ? 1.0f : ((d < 0.0f) ? __fdiv_rn(-d, 0.7f) : 0.0f);
        float hval = __fadd_rn(__fadd_rn(__fadd_rn(__fadd_rn(
                         __fmul_rn(w0, g1), __fmul_rn(w1, g2)),
                         __fmul_rn(w2, rep)), __fmul_rn(w3, hyd)), __fmul_rn(w4, hb));
        float f = (d < 8.0f) ? hval : 0.0f;
        esum = __fadd_rn(esum, f);
    }
    if (lane == 0) partials[i] = esum;
}

// ---------------------------------------------------------------------------
// Kernel 4: deterministic tree reduction + final division.
// ---------------------------------------------------------------------------
__global__ __launch_bounds__(256) void k4_reduce(const float* __restrict__ partials,
                                                 const float* __restrict__ weights,
                                                 const float* __restrict__ nrot,
                                                 float* __restrict__ out) {
    __shared__ float red[256];
    const int t = threadIdx.x;
    float s = 0.0f;
    for (int k = 0; k < NATOMS / 256; ++k) s = __fadd_rn(s, partials[t + 256 * k]);
    red[t] = s;
    __syncthreads();
    for (int off = 128; off > 0; off >>= 1) {
        if (t < off) red[t] = __fadd_rn(red[t], red[t + off]);
        __syncthreads();
    }
    if (t == 0) out[0] = __fdiv_rn(red[0], __fadd_rn(1.0f, __fmul_rn(weights[5], nrot[0])));
}

extern "C" void kernel_launch(void* const* d_in, const int* in_sizes, int n_in,
                              void* d_out, int out_size, void* d_ws, size_t ws_size,
                              hipStream_t stream) {
    const float* coords  = (const float*)d_in[0];
    const float* vdw     = (const float*)d_in[1];
    const float* weights = (const float*)d_in[2];
    const float* nrot    = (const float*)d_in[3];
    float* out = (float*)d_out;

    int* nbrTable      = (int*)d_ws;                       // 208000 ints
    int* atomsInCells  = nbrTable + NCELLS * NBRC;         // 40000
    int* cellsForAtoms = atomsInCells + NCELLS * KTOP;     // 4096
    int* neededFlag    = cellsForAtoms + NATOMS;           // 8000
    float* partials    = (float*)(neededFlag + NCELLS);    // 4096
    float4* c4         = (float4*)(partials + NATOMS);     // 4096 float4 (16B-aligned)

    k1_cells_nbr<<<NATOMS, 256, 0, stream>>>(coords, cellsForAtoms, c4,
                                             nbrTable, neededFlag);
    k2_atoms<<<NCELLS, 256, 0, stream>>>(c4, neededFlag, atomsInCells);
    k3_energy<<<NATOMS / 4, 256, 0, stream>>>(c4, vdw, weights, nbrTable,
                                              atomsInCells, cellsForAtoms, partials);
    k4_reduce<<<1, 256, 0, stream>>>(partials, weights, nrot, out);
}